// Round 17
// baseline (203.560 us; speedup 1.0000x reference)
//
#include <hip/hip_runtime.h>
#include <hip/hip_bf16.h>
#include <math.h>

// ---- problem constants ----
#define TOKS   65536      // B*D*H*W
#define DIMC   192
#define NTOK   128
#define MLPH   384
#define QSCALE 0.17677669529663687f

typedef unsigned short u16;
typedef unsigned int   u32;
typedef __attribute__((ext_vector_type(8))) short bf16x8;   // 16B raw move
typedef __attribute__((ext_vector_type(4))) float f32x4;

static __device__ __forceinline__ float gelu_exact(float v) {
    return 0.5f * v * (1.f + erff(v * 0.70710678118654752f));
}
static __device__ __forceinline__ u16 f2bf(float f) {
    __hip_bfloat16 h = __float2bfloat16(f);
    return *reinterpret_cast<u16*>(&h);
}
static __device__ __forceinline__ float bf2f(u16 b) {
    u32 u = ((u32)b) << 16;
    float f;
    __builtin_memcpy(&f, &u, 4);
    return f;
}
static __device__ __forceinline__ void gl_lds16(const u16* g, u16* l) {
    __builtin_amdgcn_global_load_lds(
        (const __attribute__((address_space(1))) void*)g,
        (__attribute__((address_space(3))) void*)l, 16, 0, 0);
}

// workspace layout (float offsets). bf16 buffers occupy elems/2 floats.
#define OFF_XW   0u          // xw bf16 (LN1 out) -> attn_out bf16 overlay
#define OFF_Q    6291456u    // q bf16 [wh][t][32]; h bf16 [65536][384] overlays Q..V
#define OFF_K    12582912u   // k bf16
#define OFF_V    18874368u   // vT bf16 [wh][d][128]; ybu (LN2 out) overlay after attn
#define OFF_BF   25165824u   // biasw bf16 [6][128][128] (fragment-tiled)
#define OFF_WB   25264128u   // bf16 weights: qkv | proj @110592 | fc1 @147456 | fc2 @221184

// ---------------- prep: weight fp32->bf16 (1152 blocks) + bias gather (384 blocks) ----------------
__global__ __launch_bounds__(256) void k_prep(const float* __restrict__ a,
                                              const float* __restrict__ b,
                                              const float* __restrict__ c,
                                              const float* __restrict__ d,
                                              u16* __restrict__ o,
                                              const float* __restrict__ rpb,
                                              const int* __restrict__ rpi,
                                              u16* __restrict__ biasw) {
    int bid = blockIdx.x;
    if (bid < 1152) {
        int i = bid * 256 + threadIdx.x;          // 294912 exact
        float v;
        if (i < 110592) v = a[i];
        else if (i < 147456) v = b[i - 110592];
        else if (i < 221184) v = c[i - 147456];
        else v = d[i - 221184];
        o[i] = f2bf(v);
    } else {
        int idx = (bid - 1152) * 256 + threadIdx.x;   // 98304 exact
        int h = idx >> 14;
        int n = (idx >> 7) & 127;
        int slot = idx & 127;
        int m = ((slot & 7) << 4) + (slot >> 3);
        biasw[idx] = f2bf(rpb[rpi[n * 128 + m] * 6 + h]);
    }
}

// ---------------- LayerNorm -> bf16 (opt. fused roll+window gather) ----------------
template<bool PERMUTE>
__global__ __launch_bounds__(256) void k_ln(const float* __restrict__ x,
                                            const float* __restrict__ gamma,
                                            const float* __restrict__ beta,
                                            u16* __restrict__ out) {
    int tid  = threadIdx.x;
    int lane = tid & 63, wv = tid >> 6;
    int tk = blockIdx.x * 4 + wv;
    size_t src;
    if (PERMUTE) {
        int w_all = tk >> 7, t = tk & 127;
        int b  = w_all >> 8, rem = w_all & 255;
        int di = rem >> 6, hi = (rem >> 3) & 7, wi = rem & 7;
        int qd = (di * 2 + (t >> 6) + 1) & 7;
        int qh = (hi * 8 + ((t >> 3) & 7) + 4) & 63;
        int qw = (wi * 8 + (t & 7) + 4) & 63;
        src = ((size_t)(((b * 8 + qd) * 64 + qh) * 64 + qw)) * DIMC;
    } else {
        src = (size_t)tk * DIMC;
    }
    float v0 = x[src + lane];
    float v1 = x[src + 64 + lane];
    float v2 = x[src + 128 + lane];
    float s  = v0 + v1 + v2;
    float sq = v0 * v0 + v1 * v1 + v2 * v2;
    #pragma unroll
    for (int off = 32; off; off >>= 1) {
        s  += __shfl_xor(s, off);
        sq += __shfl_xor(sq, off);
    }
    float mu   = s * (1.f / 192.f);
    float var  = sq * (1.f / 192.f) - mu * mu;
    float rstd = rsqrtf(var + 1e-5f);
    size_t o = (size_t)tk * DIMC;
    out[o + lane]       = f2bf((v0 - mu) * rstd * gamma[lane]       + beta[lane]);
    out[o + 64 + lane]  = f2bf((v1 - mu) * rstd * gamma[64 + lane]  + beta[64 + lane]);
    out[o + 128 + lane] = f2bf((v2 - mu) * rstd * gamma[128 + lane] + beta[128 + lane]);
}

// ---------------- bf16 MFMA GEMM (R14 + NS m-stripes per block) ----------------
// NS stripes share one block: W-hoist loaded once, K-loop+epilogue run NS times.
// Halves block count for QKV/fc1 (the two dispatches 3-4x above their HBM floor,
// where per-block fixed cost dominates). proj/fc2 (at HBM floor) keep NS=1.
// 1D grid; logical = (bid%8)*(nwg/8)+bid/8; xb=logical/NY, yb=logical%NY.
// MODE 0: QKV -> q/k bf16 [wh][t][32] (q scaled), vT bf16 [wh][d][128] (LDS transpose)
// MODE 1: proj -> roll-reverse scatter += aux(x) -> xres fp32
// MODE 2: fc1 -> gelu -> h bf16 [m][384]
// MODE 3: fc2 (K=384) -> += aux -> xres fp32
template<int MODE, int KD, int NS>
__global__ __launch_bounds__(256) void k_mgemm(const u16* __restrict__ A,
                                               const u16* __restrict__ W,
                                               const float* __restrict__ bias,
                                               void* __restrict__ outp,
                                               const float* __restrict__ aux,
                                               u16* __restrict__ q_o,
                                               u16* __restrict__ k_o,
                                               u16* __restrict__ v_o) {
    __shared__ u16 As[2][128 * 64];          // 32 KB; epilogue bounce aliases
    u16*   Eu = (u16*)As;
    float* Ef = (float*)As;
    const int tid = threadIdx.x;
    const int wv = tid >> 6, l = tid & 63;
    const int l15 = l & 15, g4 = l >> 4;
    const int wm = wv >> 1, wn = wv & 1;
    constexpr int NY  = (MODE == 0) ? 9 : (MODE == 2) ? 6 : 3;
    constexpr int CHK = (512 / NS) * NY / 8;     // blocks per XCD
    const int bid = blockIdx.x;
    const int logical = (bid & 7) * CHK + (bid >> 3);
    const int xb = logical / NY;
    const int yb = logical - xb * NY;
    const int n0 = yb * 64;
    const int srow = l >> 3, scol = l & 7;

    // ---- pre-hoist W fragments for k-tiles 0..2 (12 x bf16x8 = 48 VGPR); reused across stripes ----
    const u16* Wb = W + (size_t)(n0 + wn * 32 + l15) * KD + g4 * 8;
    bf16x8 wfr[3][2][2];
    #pragma unroll
    for (int t = 0; t < 3; ++t)
        #pragma unroll
        for (int kk = 0; kk < 2; ++kk)
            #pragma unroll
            for (int nt = 0; nt < 2; ++nt)
                wfr[t][kk][nt] = *(const bf16x8*)&Wb[(size_t)(nt * 16) * KD + t * 64 + kk * 32];

    #pragma unroll 1
    for (int s = 0; s < NS; ++s) {
        const size_t m0 = ((size_t)xb * NS + s) * 128;
        const int w = (int)(m0 >> 7);
        f32x4 acc[4][2] = {};

        auto STAGE = [&](int b, int tcol) {
            const u16* Ab = A + m0 * KD + tcol * 64;
            #pragma unroll
            for (int j = 0; j < 4; ++j) {
                int row = (wv * 4 + j) * 8 + srow;
                int sc  = scol ^ (row & 7);
                gl_lds16(Ab + (size_t)row * KD + sc * 8, &As[b][(wv * 4 + j) * 512]);
            }
        };
        auto COMPUTE = [&](int b, int t) {
            #pragma unroll
            for (int kk = 0; kk < 2; ++kk) {
                bf16x8 bfr[2];
                if (t < 3) {
                    bfr[0] = wfr[t][kk][0];
                    bfr[1] = wfr[t][kk][1];
                } else {
                    #pragma unroll
                    for (int nt = 0; nt < 2; ++nt)
                        bfr[nt] = *(const bf16x8*)&Wb[(size_t)(nt * 16) * KD + t * 64 + kk * 32];
                }
                #pragma unroll
                for (int mt = 0; mt < 4; ++mt) {
                    int row  = wm * 64 + mt * 16 + l15;
                    int slot = (kk * 4 + g4) ^ (row & 7);
                    bf16x8 afr = *(const bf16x8*)&As[b][row * 64 + slot * 8];
                    #pragma unroll
                    for (int nt = 0; nt < 2; ++nt)
                        acc[mt][nt] = __builtin_amdgcn_mfma_f32_16x16x32_bf16(afr, bfr[nt],
                                                                              acc[mt][nt], 0, 0, 0);
                }
            }
        };

        constexpr int NT = KD / 64;
        STAGE(0, 0);
        __syncthreads();
        #pragma unroll
        for (int t = 0; t < NT; ++t) {
            if (t + 1 < NT) STAGE((t + 1) & 1, t + 1);
            COMPUTE(t & 1, t);
            __syncthreads();
        }
        // As is dead now (all waves passed the final barrier).

        if (MODE == 0 || MODE == 2) {
            // ---- stage bf16 tile [128 r][64 c], slot8 = (c>>3) ^ ((r>>2)&7) ----
            const int sel = (MODE == 0) ? ((n0 >= 384) ? 2 : (n0 >= 192 ? 1 : 0)) : 0;
            const float scl = (MODE == 0 && sel == 0) ? QSCALE : 1.f;
            #pragma unroll
            for (int mt = 0; mt < 4; ++mt) {
                #pragma unroll
                for (int nt = 0; nt < 2; ++nt) {
                    int c = wn * 32 + nt * 16 + l15;
                    float bb = bias[n0 + c];
                    #pragma unroll
                    for (int reg = 0; reg < 4; ++reg) {
                        int r = wm * 64 + mt * 16 + g4 * 4 + reg;
                        float v = acc[mt][nt][reg] + bb;
                        if (MODE == 2) v = gelu_exact(v);
                        else v *= scl;
                        int slot8 = (c >> 3) ^ ((r >> 2) & 7);
                        Eu[r * 64 + slot8 * 8 + (c & 7)] = f2bf(v);
                    }
                }
            }
            __syncthreads();
            if (MODE == 2) {
                u16* out = (u16*)outp;
                #pragma unroll
                for (int p = 0; p < 4; ++p) {               // 1024 chunks of 16B
                    int cid = p * 256 + tid;
                    int r = cid >> 3, j = cid & 7;
                    int slot8 = j ^ ((r >> 2) & 7);
                    bf16x8 vv = *(const bf16x8*)&Eu[r * 64 + slot8 * 8];
                    *(bf16x8*)&out[(m0 + r) * MLPH + n0 + j * 8] = vv;
                }
            } else if (sel < 2) {
                // q/k: row r -> head hbase+(c0>>5), contiguous 64B per head
                u16* dst = sel ? k_o : q_o;
                const int hbase = (n0 - sel * 192) >> 5;
                #pragma unroll
                for (int p = 0; p < 4; ++p) {
                    int cid = p * 256 + tid;
                    int r = cid >> 3, j = cid & 7;
                    int c0 = j * 8;
                    int slot8 = j ^ ((r >> 2) & 7);
                    bf16x8 vv = *(const bf16x8*)&Eu[r * 64 + slot8 * 8];
                    size_t b9 = (size_t)(w * 6 + hbase + (c0 >> 5)) * 4096;
                    *(bf16x8*)&dst[b9 + (size_t)r * 32 + (c0 & 31)] = vv;
                }
            } else {
                // v: transpose in LDS -> rows of vT [d][128] (256B contiguous)
                const int hbase = (n0 - 384) >> 5;
                #pragma unroll
                for (int p = 0; p < 4; ++p) {               // 64 c-rows x 16 chunks
                    int cid = p * 256 + tid;
                    int c = cid >> 4, jt = cid & 15;
                    int t0 = jt * 8;
                    u16 tmp[8];
                    #pragma unroll
                    for (int i = 0; i < 8; ++i) {
                        int r = t0 + i;
                        int slot8 = (c >> 3) ^ ((r >> 2) & 7);
                        tmp[i] = Eu[r * 64 + slot8 * 8 + (c & 7)];
                    }
                    size_t b9 = (size_t)(w * 6 + hbase + (c >> 5)) * 4096;
                    *(bf16x8*)&v_o[b9 + (size_t)(c & 31) * 128 + t0] = *(bf16x8*)tmp;
                }
            }
        } else {
            // ---- MODE 1 / 3: fp32 bounce [128 r][64 c], swz = (c>>2) ^ ((r>>2)&3) ----
            #pragma unroll
            for (int mt = 0; mt < 4; ++mt) {
                #pragma unroll
                for (int nt = 0; nt < 2; ++nt) {
                    int c = wn * 32 + nt * 16 + l15;
                    float bb = bias[n0 + c];
                    #pragma unroll
                    for (int reg = 0; reg < 4; ++reg) {
                        int r = wm * 64 + mt * 16 + g4 * 4 + reg;
                        int swz = (c >> 2) ^ ((r >> 2) & 3);
                        Ef[r * 64 + swz * 4 + (c & 3)] = acc[mt][nt][reg] + bb;
                    }
                }
            }
            __syncthreads();
            float* out = (float*)outp;
            #pragma unroll
            for (int p = 0; p < 8; ++p) {                   // 2048 chunks of 16B
                int cid = p * 256 + tid;
                int r = cid >> 4, j = cid & 15;
                int swz = j ^ ((r >> 2) & 3);
                float4 vv = *(const float4*)&Ef[r * 64 + swz * 4];
                size_t drow;
                if (MODE == 1) {
                    int m = (int)m0 + r;
                    int w_all = m >> 7, tt = m & 127;
                    int b  = w_all >> 8, rem = w_all & 255;
                    int di = rem >> 6, hi = (rem >> 3) & 7, wi = rem & 7;
                    int qd = (di * 2 + (tt >> 6) + 1) & 7;
                    int qh = (hi * 8 + ((tt >> 3) & 7) + 4) & 63;
                    int qw = (wi * 8 + (tt & 7) + 4) & 63;
                    drow = (size_t)(((b * 8 + qd) * 64 + qh) * 64 + qw) * DIMC;
                } else {
                    drow = (m0 + r) * DIMC;
                }
                float4 ax = *(const float4*)&aux[drow + n0 + j * 4];
                vv.x += ax.x; vv.y += ax.y; vv.z += ax.z; vv.w += ax.w;
                *(float4*)&out[drow + n0 + j * 4] = vv;
            }
        }
        if (NS > 1) __syncthreads();   // all Eu reads done before next stripe's STAGE
    }
}

// ---------------- MFMA attention (R8-validated, unchanged) ----------------
__global__ __launch_bounds__(256) void k_attn(const u16* __restrict__ qb,
                                              const u16* __restrict__ kb,
                                              const u16* __restrict__ vb,
                                              const u16* __restrict__ biasw,
                                              u16* __restrict__ attn_out) {
    __shared__ u16 Pl[4][32 * 128];     // 32 KB; O-bounce aliases this
    u16* Ou = (u16*)Pl;                  // [128][32] swizzled
    int wh = blockIdx.x;
    int w_all = wh / 6, head = wh - w_all * 6;
    int wl = w_all & 255;
    int tid = threadIdx.x;
    int wv = tid >> 6, l = tid & 63;
    int l15 = l & 15, g4 = l >> 4;
    size_t base = (size_t)wh * 4096;
    const u16* qg = qb + base;
    const u16* kg = kb + base;
    const u16* vg = vb + base;           // [d][m]
    int rowb = wv * 32;

    bf16x8 qa[2];
    #pragma unroll
    for (int rt = 0; rt < 2; ++rt)
        qa[rt] = *(const bf16x8*)&qg[(size_t)(rowb + rt * 16 + l15) * 32 + g4 * 8];

    f32x4 s[2][8] = {};
    #pragma unroll
    for (int ct = 0; ct < 8; ++ct) {
        bf16x8 kf = *(const bf16x8*)&kg[(size_t)(ct * 16 + l15) * 32 + g4 * 8];
        s[0][ct] = __builtin_amdgcn_mfma_f32_16x16x32_bf16(qa[0], kf, s[0][ct], 0, 0, 0);
        s[1][ct] = __builtin_amdgcn_mfma_f32_16x16x32_bf16(qa[1], kf, s[1][ct], 0, 0, 0);
    }

    int di = wl >> 6, hi = (wl >> 3) & 7, wi = wl & 7;
    auto rcode = [&](int t) {
        int d = di * 2 + (t >> 6);
        int h = hi * 8 + ((t >> 3) & 7);
        int w = wi * 8 + (t & 7);
        int rd = (d < 6) ? 0 : (d < 7 ? 1 : 2);
        int rh = (h < 56) ? 0 : (h < 60 ? 1 : 2);
        int rw = (w < 56) ? 0 : (w < 60 ? 1 : 2);
        return rd * 9 + rh * 3 + rw;
    };
    int rm[8];
    #pragma unroll
    for (int ct = 0; ct < 8; ++ct) rm[ct] = rcode(ct * 16 + l15);

    const u16* bh = biasw + (size_t)head * 16384;
    #pragma unroll
    for (int rt = 0; rt < 2; ++rt)
        #pragma unroll
        for (int reg = 0; reg < 4; ++reg) {
            int n = rowb + rt * 16 + g4 * 4 + reg;
            int rn = rcode(n);
            bf16x8 bv = *(const bf16x8*)&bh[(size_t)n * 128 + l15 * 8];
            #pragma unroll
            for (int ct = 0; ct < 8; ++ct) {
                float mval = (rn == rm[ct]) ? 0.f : -100.f;
                s[rt][ct][reg] += bf2f((u16)bv[ct]) + mval;
            }
        }

    u16* Pw = Pl[wv];
    #pragma unroll
    for (int rt = 0; rt < 2; ++rt)
        #pragma unroll
        for (int reg = 0; reg < 4; ++reg) {
            float mx = -1e30f;
            #pragma unroll
            for (int ct = 0; ct < 8; ++ct) mx = fmaxf(mx, s[rt][ct][reg]);
            #pragma unroll
            for (int off = 1; off < 16; off <<= 1) mx = fmaxf(mx, __shfl_xor(mx, off));
            float sum = 0.f;
            #pragma unroll
            for (int ct = 0; ct < 8; ++ct) {
                float p = __expf(s[rt][ct][reg] - mx);
                s[rt][ct][reg] = p; sum += p;
            }
            #pragma unroll
            for (int off = 1; off < 16; off <<= 1) sum += __shfl_xor(sum, off);
            float inv = 1.f / sum;
            int nloc = rt * 16 + g4 * 4 + reg;
            int sw = ((nloc >> 2) & 3) << 4;
            #pragma unroll
            for (int ct = 0; ct < 8; ++ct) {
                int m = ct * 16 + l15;
                Pw[nloc * 128 + (m ^ sw)] = f2bf(s[rt][ct][reg] * inv);
            }
        }
    __syncthreads();

    f32x4 o[2][2] = {};
    #pragma unroll
    for (int kt = 0; kt < 4; ++kt) {
        bf16x8 vf[2];
        #pragma unroll
        for (int dt = 0; dt < 2; ++dt)
            vf[dt] = *(const bf16x8*)&vg[(size_t)(dt * 16 + l15) * 128 + kt * 32 + g4 * 8];
        #pragma unroll
        for (int rt = 0; rt < 2; ++rt) {
            int nloc = rt * 16 + l15;
            int sw = ((nloc >> 2) & 3) << 4;
            int m8 = kt * 32 + g4 * 8;
            bf16x8 pa = *(const bf16x8*)&Pw[nloc * 128 + (m8 ^ sw)];
            #pragma unroll
            for (int dt = 0; dt < 2; ++dt)
                o[rt][dt] = __builtin_amdgcn_mfma_f32_16x16x32_bf16(pa, vf[dt], o[rt][dt], 0, 0, 0);
        }
    }

    __syncthreads();                      // Pl dead
    #pragma unroll
    for (int rt = 0; rt < 2; ++rt)
        #pragma unroll
        for (int dt = 0; dt < 2; ++dt)
            #pragma unroll
            for (int reg = 0; reg < 4; ++reg) {
                int r = rowb + rt * 16 + g4 * 4 + reg;
                int c = dt * 16 + l15;
                int slot8 = (c >> 3) ^ ((r >> 2) & 3);
                Ou[r * 32 + slot8 * 8 + (c & 7)] = f2bf(o[rt][dt][reg]);
            }
    __syncthreads();
    #pragma unroll
    for (int p = 0; p < 2; ++p) {         // 512 chunks of 16B
        int cid = p * 256 + tid;
        int r = cid >> 2, j = cid & 3;
        int slot8 = j ^ ((r >> 2) & 3);
        bf16x8 vv = *(const bf16x8*)&Ou[r * 32 + slot8 * 8];
        *(bf16x8*)&attn_out[((size_t)(w_all * 128 + r)) * DIMC + head * 32 + j * 8] = vv;
    }
}

// ---------------- launch ----------------
extern "C" void kernel_launch(void* const* d_in, const int* in_sizes, int n_in,
                              void* d_out, int out_size, void* d_ws, size_t ws_size,
                              hipStream_t stream) {
    const float* x      = (const float*)d_in[0];
    const int*   rpi    = (const int*)d_in[2];
    const float* gamma1 = (const float*)d_in[3];
    const float* beta1  = (const float*)d_in[4];
    const float* w_qkv  = (const float*)d_in[5];
    const float* b_qkv  = (const float*)d_in[6];
    const float* rpb    = (const float*)d_in[7];
    const float* w_proj = (const float*)d_in[8];
    const float* b_proj = (const float*)d_in[9];
    const float* gamma2 = (const float*)d_in[10];
    const float* beta2  = (const float*)d_in[11];
    const float* w_fc1  = (const float*)d_in[12];
    const float* b_fc1  = (const float*)d_in[13];
    const float* w_fc2  = (const float*)d_in[14];
    const float* b_fc2  = (const float*)d_in[15];

    float* ws    = (float*)d_ws;
    u16*   xwu   = (u16*)(ws + OFF_XW);   // LN1 out; attn_out overlay after QKV
    u16*   qbu   = (u16*)(ws + OFF_Q);
    u16*   kbu   = (u16*)(ws + OFF_K);
    u16*   vbu   = (u16*)(ws + OFF_V);
    u16*   hbu   = (u16*)(ws + OFF_Q);    // fc1 out overlays q..v (dead after attn)
    u16*   ybu   = (u16*)(ws + OFF_V);    // LN2 out overlays vT (dead after attn)
    u16*   biasw = (u16*)(ws + OFF_BF);
    u16*   wb    = (u16*)(ws + OFF_WB);
    float* xres  = (float*)d_out;

    const u16* wqkv_b  = wb;
    const u16* wproj_b = wb + 110592;
    const u16* wfc1_b  = wb + 147456;
    const u16* wfc2_b  = wb + 221184;

    k_prep<<<1536, 256, 0, stream>>>(w_qkv, w_proj, w_fc1, w_fc2, wb, rpb, rpi, biasw);
    k_ln<true><<<16384, 256, 0, stream>>>(x, gamma1, beta1, xwu);
    k_mgemm<0, 192, 2><<<2304, 256, 0, stream>>>(xwu, wqkv_b, b_qkv, nullptr, nullptr,
                                                 qbu, kbu, vbu);
    k_attn<<<3072, 256, 0, stream>>>(qbu, kbu, vbu, biasw, xwu);
    k_mgemm<1, 192, 1><<<1536, 256, 0, stream>>>(xwu, wproj_b, b_proj, xres, x,
                                                 nullptr, nullptr, nullptr);
    k_ln<false><<<16384, 256, 0, stream>>>(xres, gamma2, beta2, ybu);
    k_mgemm<2, 192, 2><<<1536, 256, 0, stream>>>(ybu, wfc1_b, b_fc1, hbu, nullptr,
                                                 nullptr, nullptr, nullptr);
    k_mgemm<3, 384, 1><<<1536, 256, 0, stream>>>(hbu, wfc2_b, b_fc2, xres, xres,
                                                 nullptr, nullptr, nullptr);
}

// Round 18
// 200.354 us; speedup vs baseline: 1.0160x; 1.0160x over previous
//
#include <hip/hip_runtime.h>
#include <hip/hip_bf16.h>
#include <math.h>

// ---- problem constants ----
#define TOKS   65536      // B*D*H*W
#define DIMC   192
#define NTOK   128
#define MLPH   384
#define QSCALE 0.17677669529663687f

typedef unsigned short u16;
typedef unsigned int   u32;
typedef __attribute__((ext_vector_type(8))) short bf16x8;   // 16B raw move
typedef __attribute__((ext_vector_type(4))) float f32x4;

static __device__ __forceinline__ float gelu_exact(float v) {
    return 0.5f * v * (1.f + erff(v * 0.70710678118654752f));
}
static __device__ __forceinline__ u16 f2bf(float f) {
    __hip_bfloat16 h = __float2bfloat16(f);
    return *reinterpret_cast<u16*>(&h);
}
static __device__ __forceinline__ float bf2f(u16 b) {
    u32 u = ((u32)b) << 16;
    float f;
    __builtin_memcpy(&f, &u, 4);
    return f;
}
static __device__ __forceinline__ void gl_lds16(const u16* g, u16* l) {
    __builtin_amdgcn_global_load_lds(
        (const __attribute__((address_space(1))) void*)g,
        (__attribute__((address_space(3))) void*)l, 16, 0, 0);
}

// workspace layout (float offsets). bf16 buffers occupy elems/2 floats.
#define OFF_XW   0u          // xw bf16 (LN1 out) -> attn_out bf16 overlay
#define OFF_Q    6291456u    // q bf16 [wh][t][32]; h bf16 [65536][384] overlays Q..V
#define OFF_K    12582912u   // k bf16
#define OFF_V    18874368u   // vT bf16 [wh][d][128]; ybu (LN2 out) overlay after attn
#define OFF_BF   25165824u   // biasw bf16 [6][128][128] (fragment-tiled)
#define OFF_WB   25264128u   // bf16 weights: qkv | proj @110592 | fc1 @147456 | fc2 @221184

// ---------------- prep: weight fp32->bf16 (1152 blocks) + bias gather (384 blocks) ----------------
__global__ __launch_bounds__(256) void k_prep(const float* __restrict__ a,
                                              const float* __restrict__ b,
                                              const float* __restrict__ c,
                                              const float* __restrict__ d,
                                              u16* __restrict__ o,
                                              const float* __restrict__ rpb,
                                              const int* __restrict__ rpi,
                                              u16* __restrict__ biasw) {
    int bid = blockIdx.x;
    if (bid < 1152) {
        int i = bid * 256 + threadIdx.x;          // 294912 exact
        float v;
        if (i < 110592) v = a[i];
        else if (i < 147456) v = b[i - 110592];
        else if (i < 221184) v = c[i - 147456];
        else v = d[i - 221184];
        o[i] = f2bf(v);
    } else {
        int idx = (bid - 1152) * 256 + threadIdx.x;   // 98304 exact
        int h = idx >> 14;
        int n = (idx >> 7) & 127;
        int slot = idx & 127;
        int m = ((slot & 7) << 4) + (slot >> 3);
        biasw[idx] = f2bf(rpb[rpi[n * 128 + m] * 6 + h]);
    }
}

// ---------------- LayerNorm -> bf16 (opt. fused roll+window gather) ----------------
template<bool PERMUTE>
__global__ __launch_bounds__(256) void k_ln(const float* __restrict__ x,
                                            const float* __restrict__ gamma,
                                            const float* __restrict__ beta,
                                            u16* __restrict__ out) {
    int tid  = threadIdx.x;
    int lane = tid & 63, wv = tid >> 6;
    int tk = blockIdx.x * 4 + wv;
    size_t src;
    if (PERMUTE) {
        int w_all = tk >> 7, t = tk & 127;
        int b  = w_all >> 8, rem = w_all & 255;
        int di = rem >> 6, hi = (rem >> 3) & 7, wi = rem & 7;
        int qd = (di * 2 + (t >> 6) + 1) & 7;
        int qh = (hi * 8 + ((t >> 3) & 7) + 4) & 63;
        int qw = (wi * 8 + (t & 7) + 4) & 63;
        src = ((size_t)(((b * 8 + qd) * 64 + qh) * 64 + qw)) * DIMC;
    } else {
        src = (size_t)tk * DIMC;
    }
    float v0 = x[src + lane];
    float v1 = x[src + 64 + lane];
    float v2 = x[src + 128 + lane];
    float s  = v0 + v1 + v2;
    float sq = v0 * v0 + v1 * v1 + v2 * v2;
    #pragma unroll
    for (int off = 32; off; off >>= 1) {
        s  += __shfl_xor(s, off);
        sq += __shfl_xor(sq, off);
    }
    float mu   = s * (1.f / 192.f);
    float var  = sq * (1.f / 192.f) - mu * mu;
    float rstd = rsqrtf(var + 1e-5f);
    size_t o = (size_t)tk * DIMC;
    out[o + lane]       = f2bf((v0 - mu) * rstd * gamma[lane]       + beta[lane]);
    out[o + 64 + lane]  = f2bf((v1 - mu) * rstd * gamma[64 + lane]  + beta[64 + lane]);
    out[o + 128 + lane] = f2bf((v2 - mu) * rstd * gamma[128 + lane] + beta[128 + lane]);
}

// ---------------- bf16 MFMA GEMM (R13 + XCD-aware y-inner grid swizzle) ----------------
// 1D grid; logical = (bid%8)*(nwg/8)+bid/8; x=logical/NY (A stripe), y=logical%NY.
// Same-stripe blocks run adjacent on one XCD -> A re-reads hit that XCD's L2.
// BM=128 BN=64 BK=64, rolling 2-buffer staging, W fragments tiles 0..2 pre-hoisted.
// MODE 0: QKV -> q/k bf16 [wh][t][32] (q scaled), vT bf16 [wh][d][128] (LDS transpose)
// MODE 1: proj -> roll-reverse scatter += aux(x) -> xres fp32
// MODE 2: fc1 -> gelu -> h bf16 [m][384]
// MODE 3: fc2 (K=384) -> += aux -> xres fp32
template<int MODE, int KD>
__global__ __launch_bounds__(256) void k_mgemm(const u16* __restrict__ A,
                                               const u16* __restrict__ W,
                                               const float* __restrict__ bias,
                                               void* __restrict__ outp,
                                               const float* __restrict__ aux,
                                               u16* __restrict__ q_o,
                                               u16* __restrict__ k_o,
                                               u16* __restrict__ v_o) {
    __shared__ u16 As[2][128 * 64];          // 32 KB; epilogue bounce aliases
    u16*   Eu = (u16*)As;
    float* Ef = (float*)As;
    const int tid = threadIdx.x;
    const int wv = tid >> 6, l = tid & 63;
    const int l15 = l & 15, g4 = l >> 4;
    const int wm = wv >> 1, wn = wv & 1;
    constexpr int NY  = (MODE == 0) ? 9 : (MODE == 2) ? 6 : 3;
    constexpr int CHK = 512 * NY / 8;        // blocks per XCD
    const int bid = blockIdx.x;
    const int logical = (bid & 7) * CHK + (bid >> 3);
    const int xb = logical / NY;
    const int yb = logical - xb * NY;
    const size_t m0 = (size_t)xb * 128;
    const int n0 = yb * 64;
    const int srow = l >> 3, scol = l & 7;
    const int w = (int)(m0 >> 7);

    f32x4 acc[4][2] = {};

    // ---- pre-hoist W fragments for k-tiles 0..2 (12 x bf16x8 = 48 VGPR) ----
    const u16* Wb = W + (size_t)(n0 + wn * 32 + l15) * KD + g4 * 8;
    bf16x8 wfr[3][2][2];
    #pragma unroll
    for (int t = 0; t < 3; ++t)
        #pragma unroll
        for (int kk = 0; kk < 2; ++kk)
            #pragma unroll
            for (int nt = 0; nt < 2; ++nt)
                wfr[t][kk][nt] = *(const bf16x8*)&Wb[(size_t)(nt * 16) * KD + t * 64 + kk * 32];

    auto STAGE = [&](int b, int tcol) {
        const u16* Ab = A + m0 * KD + tcol * 64;
        #pragma unroll
        for (int j = 0; j < 4; ++j) {
            int row = (wv * 4 + j) * 8 + srow;
            int sc  = scol ^ (row & 7);
            gl_lds16(Ab + (size_t)row * KD + sc * 8, &As[b][(wv * 4 + j) * 512]);
        }
    };
    auto COMPUTE = [&](int b, int t) {
        #pragma unroll
        for (int kk = 0; kk < 2; ++kk) {
            bf16x8 bfr[2];
            if (t < 3) {
                bfr[0] = wfr[t][kk][0];
                bfr[1] = wfr[t][kk][1];
            } else {
                #pragma unroll
                for (int nt = 0; nt < 2; ++nt)
                    bfr[nt] = *(const bf16x8*)&Wb[(size_t)(nt * 16) * KD + t * 64 + kk * 32];
            }
            #pragma unroll
            for (int mt = 0; mt < 4; ++mt) {
                int row  = wm * 64 + mt * 16 + l15;
                int slot = (kk * 4 + g4) ^ (row & 7);
                bf16x8 afr = *(const bf16x8*)&As[b][row * 64 + slot * 8];
                #pragma unroll
                for (int nt = 0; nt < 2; ++nt)
                    acc[mt][nt] = __builtin_amdgcn_mfma_f32_16x16x32_bf16(afr, bfr[nt],
                                                                          acc[mt][nt], 0, 0, 0);
            }
        }
    };

    constexpr int NT = KD / 64;
    STAGE(0, 0);
    __syncthreads();
    #pragma unroll
    for (int t = 0; t < NT; ++t) {
        if (t + 1 < NT) STAGE((t + 1) & 1, t + 1);
        COMPUTE(t & 1, t);
        __syncthreads();
    }
    // As is dead now (all waves passed the final barrier).

    if (MODE == 0 || MODE == 2) {
        // ---- stage bf16 tile [128 r][64 c], slot8 = (c>>3) ^ ((r>>2)&7) ----
        const int sel = (MODE == 0) ? ((n0 >= 384) ? 2 : (n0 >= 192 ? 1 : 0)) : 0;
        const float scl = (MODE == 0 && sel == 0) ? QSCALE : 1.f;
        #pragma unroll
        for (int mt = 0; mt < 4; ++mt) {
            #pragma unroll
            for (int nt = 0; nt < 2; ++nt) {
                int c = wn * 32 + nt * 16 + l15;
                float bb = bias[n0 + c];
                #pragma unroll
                for (int reg = 0; reg < 4; ++reg) {
                    int r = wm * 64 + mt * 16 + g4 * 4 + reg;
                    float v = acc[mt][nt][reg] + bb;
                    if (MODE == 2) v = gelu_exact(v);
                    else v *= scl;
                    int slot8 = (c >> 3) ^ ((r >> 2) & 7);
                    Eu[r * 64 + slot8 * 8 + (c & 7)] = f2bf(v);
                }
            }
        }
        __syncthreads();
        if (MODE == 2) {
            u16* out = (u16*)outp;
            #pragma unroll
            for (int p = 0; p < 4; ++p) {               // 1024 chunks of 16B
                int cid = p * 256 + tid;
                int r = cid >> 3, j = cid & 7;
                int slot8 = j ^ ((r >> 2) & 7);
                bf16x8 vv = *(const bf16x8*)&Eu[r * 64 + slot8 * 8];
                *(bf16x8*)&out[(m0 + r) * MLPH + n0 + j * 8] = vv;
            }
        } else if (sel < 2) {
            // q/k: row r -> head hbase+(c0>>5), contiguous 64B per head
            u16* dst = sel ? k_o : q_o;
            const int hbase = (n0 - sel * 192) >> 5;
            #pragma unroll
            for (int p = 0; p < 4; ++p) {
                int cid = p * 256 + tid;
                int r = cid >> 3, j = cid & 7;
                int c0 = j * 8;
                int slot8 = j ^ ((r >> 2) & 7);
                bf16x8 vv = *(const bf16x8*)&Eu[r * 64 + slot8 * 8];
                size_t b9 = (size_t)(w * 6 + hbase + (c0 >> 5)) * 4096;
                *(bf16x8*)&dst[b9 + (size_t)r * 32 + (c0 & 31)] = vv;
            }
        } else {
            // v: transpose in LDS -> rows of vT [d][128] (256B contiguous)
            const int hbase = (n0 - 384) >> 5;
            #pragma unroll
            for (int p = 0; p < 4; ++p) {               // 64 c-rows x 16 chunks
                int cid = p * 256 + tid;
                int c = cid >> 4, jt = cid & 15;
                int t0 = jt * 8;
                u16 tmp[8];
                #pragma unroll
                for (int i = 0; i < 8; ++i) {
                    int r = t0 + i;
                    int slot8 = (c >> 3) ^ ((r >> 2) & 7);
                    tmp[i] = Eu[r * 64 + slot8 * 8 + (c & 7)];
                }
                size_t b9 = (size_t)(w * 6 + hbase + (c >> 5)) * 4096;
                *(bf16x8*)&v_o[b9 + (size_t)(c & 31) * 128 + t0] = *(bf16x8*)tmp;
            }
        }
    } else {
        // ---- MODE 1 / 3: fp32 bounce [128 r][64 c], swz = (c>>2) ^ ((r>>2)&3) ----
        #pragma unroll
        for (int mt = 0; mt < 4; ++mt) {
            #pragma unroll
            for (int nt = 0; nt < 2; ++nt) {
                int c = wn * 32 + nt * 16 + l15;
                float bb = bias[n0 + c];
                #pragma unroll
                for (int reg = 0; reg < 4; ++reg) {
                    int r = wm * 64 + mt * 16 + g4 * 4 + reg;
                    int swz = (c >> 2) ^ ((r >> 2) & 3);
                    Ef[r * 64 + swz * 4 + (c & 3)] = acc[mt][nt][reg] + bb;
                }
            }
        }
        __syncthreads();
        float* out = (float*)outp;
        #pragma unroll
        for (int p = 0; p < 8; ++p) {                   // 2048 chunks of 16B
            int cid = p * 256 + tid;
            int r = cid >> 4, j = cid & 15;
            int swz = j ^ ((r >> 2) & 3);
            float4 vv = *(const float4*)&Ef[r * 64 + swz * 4];
            size_t drow;
            if (MODE == 1) {
                int m = (int)m0 + r;
                int w_all = m >> 7, tt = m & 127;
                int b  = w_all >> 8, rem = w_all & 255;
                int di = rem >> 6, hi = (rem >> 3) & 7, wi = rem & 7;
                int qd = (di * 2 + (tt >> 6) + 1) & 7;
                int qh = (hi * 8 + ((tt >> 3) & 7) + 4) & 63;
                int qw = (wi * 8 + (tt & 7) + 4) & 63;
                drow = (size_t)(((b * 8 + qd) * 64 + qh) * 64 + qw) * DIMC;
            } else {
                drow = (m0 + r) * DIMC;
            }
            float4 ax = *(const float4*)&aux[drow + n0 + j * 4];
            vv.x += ax.x; vv.y += ax.y; vv.z += ax.z; vv.w += ax.w;
            *(float4*)&out[drow + n0 + j * 4] = vv;
        }
    }
}

// ---------------- MFMA attention (R8-validated, unchanged) ----------------
__global__ __launch_bounds__(256) void k_attn(const u16* __restrict__ qb,
                                              const u16* __restrict__ kb,
                                              const u16* __restrict__ vb,
                                              const u16* __restrict__ biasw,
                                              u16* __restrict__ attn_out) {
    __shared__ u16 Pl[4][32 * 128];     // 32 KB; O-bounce aliases this
    u16* Ou = (u16*)Pl;                  // [128][32] swizzled
    int wh = blockIdx.x;
    int w_all = wh / 6, head = wh - w_all * 6;
    int wl = w_all & 255;
    int tid = threadIdx.x;
    int wv = tid >> 6, l = tid & 63;
    int l15 = l & 15, g4 = l >> 4;
    size_t base = (size_t)wh * 4096;
    const u16* qg = qb + base;
    const u16* kg = kb + base;
    const u16* vg = vb + base;           // [d][m]
    int rowb = wv * 32;

    bf16x8 qa[2];
    #pragma unroll
    for (int rt = 0; rt < 2; ++rt)
        qa[rt] = *(const bf16x8*)&qg[(size_t)(rowb + rt * 16 + l15) * 32 + g4 * 8];

    f32x4 s[2][8] = {};
    #pragma unroll
    for (int ct = 0; ct < 8; ++ct) {
        bf16x8 kf = *(const bf16x8*)&kg[(size_t)(ct * 16 + l15) * 32 + g4 * 8];
        s[0][ct] = __builtin_amdgcn_mfma_f32_16x16x32_bf16(qa[0], kf, s[0][ct], 0, 0, 0);
        s[1][ct] = __builtin_amdgcn_mfma_f32_16x16x32_bf16(qa[1], kf, s[1][ct], 0, 0, 0);
    }

    int di = wl >> 6, hi = (wl >> 3) & 7, wi = wl & 7;
    auto rcode = [&](int t) {
        int d = di * 2 + (t >> 6);
        int h = hi * 8 + ((t >> 3) & 7);
        int w = wi * 8 + (t & 7);
        int rd = (d < 6) ? 0 : (d < 7 ? 1 : 2);
        int rh = (h < 56) ? 0 : (h < 60 ? 1 : 2);
        int rw = (w < 56) ? 0 : (w < 60 ? 1 : 2);
        return rd * 9 + rh * 3 + rw;
    };
    int rm[8];
    #pragma unroll
    for (int ct = 0; ct < 8; ++ct) rm[ct] = rcode(ct * 16 + l15);

    const u16* bh = biasw + (size_t)head * 16384;
    #pragma unroll
    for (int rt = 0; rt < 2; ++rt)
        #pragma unroll
        for (int reg = 0; reg < 4; ++reg) {
            int n = rowb + rt * 16 + g4 * 4 + reg;
            int rn = rcode(n);
            bf16x8 bv = *(const bf16x8*)&bh[(size_t)n * 128 + l15 * 8];
            #pragma unroll
            for (int ct = 0; ct < 8; ++ct) {
                float mval = (rn == rm[ct]) ? 0.f : -100.f;
                s[rt][ct][reg] += bf2f((u16)bv[ct]) + mval;
            }
        }

    u16* Pw = Pl[wv];
    #pragma unroll
    for (int rt = 0; rt < 2; ++rt)
        #pragma unroll
        for (int reg = 0; reg < 4; ++reg) {
            float mx = -1e30f;
            #pragma unroll
            for (int ct = 0; ct < 8; ++ct) mx = fmaxf(mx, s[rt][ct][reg]);
            #pragma unroll
            for (int off = 1; off < 16; off <<= 1) mx = fmaxf(mx, __shfl_xor(mx, off));
            float sum = 0.f;
            #pragma unroll
            for (int ct = 0; ct < 8; ++ct) {
                float p = __expf(s[rt][ct][reg] - mx);
                s[rt][ct][reg] = p; sum += p;
            }
            #pragma unroll
            for (int off = 1; off < 16; off <<= 1) sum += __shfl_xor(sum, off);
            float inv = 1.f / sum;
            int nloc = rt * 16 + g4 * 4 + reg;
            int sw = ((nloc >> 2) & 3) << 4;
            #pragma unroll
            for (int ct = 0; ct < 8; ++ct) {
                int m = ct * 16 + l15;
                Pw[nloc * 128 + (m ^ sw)] = f2bf(s[rt][ct][reg] * inv);
            }
        }
    __syncthreads();

    f32x4 o[2][2] = {};
    #pragma unroll
    for (int kt = 0; kt < 4; ++kt) {
        bf16x8 vf[2];
        #pragma unroll
        for (int dt = 0; dt < 2; ++dt)
            vf[dt] = *(const bf16x8*)&vg[(size_t)(dt * 16 + l15) * 128 + kt * 32 + g4 * 8];
        #pragma unroll
        for (int rt = 0; rt < 2; ++rt) {
            int nloc = rt * 16 + l15;
            int sw = ((nloc >> 2) & 3) << 4;
            int m8 = kt * 32 + g4 * 8;
            bf16x8 pa = *(const bf16x8*)&Pw[nloc * 128 + (m8 ^ sw)];
            #pragma unroll
            for (int dt = 0; dt < 2; ++dt)
                o[rt][dt] = __builtin_amdgcn_mfma_f32_16x16x32_bf16(pa, vf[dt], o[rt][dt], 0, 0, 0);
        }
    }

    __syncthreads();                      // Pl dead
    #pragma unroll
    for (int rt = 0; rt < 2; ++rt)
        #pragma unroll
        for (int dt = 0; dt < 2; ++dt)
            #pragma unroll
            for (int reg = 0; reg < 4; ++reg) {
                int r = rowb + rt * 16 + g4 * 4 + reg;
                int c = dt * 16 + l15;
                int slot8 = (c >> 3) ^ ((r >> 2) & 3);
                Ou[r * 32 + slot8 * 8 + (c & 7)] = f2bf(o[rt][dt][reg]);
            }
    __syncthreads();
    #pragma unroll
    for (int p = 0; p < 2; ++p) {         // 512 chunks of 16B
        int cid = p * 256 + tid;
        int r = cid >> 2, j = cid & 3;
        int slot8 = j ^ ((r >> 2) & 3);
        bf16x8 vv = *(const bf16x8*)&Ou[r * 32 + slot8 * 8];
        *(bf16x8*)&attn_out[((size_t)(w_all * 128 + r)) * DIMC + head * 32 + j * 8] = vv;
    }
}

// ---------------- launch ----------------
extern "C" void kernel_launch(void* const* d_in, const int* in_sizes, int n_in,
                              void* d_out, int out_size, void* d_ws, size_t ws_size,
                              hipStream_t stream) {
    const float* x      = (const float*)d_in[0];
    const int*   rpi    = (const int*)d_in[2];
    const float* gamma1 = (const float*)d_in[3];
    const float* beta1  = (const float*)d_in[4];
    const float* w_qkv  = (const float*)d_in[5];
    const float* b_qkv  = (const float*)d_in[6];
    const float* rpb    = (const float*)d_in[7];
    const float* w_proj = (const float*)d_in[8];
    const float* b_proj = (const float*)d_in[9];
    const float* gamma2 = (const float*)d_in[10];
    const float* beta2  = (const float*)d_in[11];
    const float* w_fc1  = (const float*)d_in[12];
    const float* b_fc1  = (const float*)d_in[13];
    const float* w_fc2  = (const float*)d_in[14];
    const float* b_fc2  = (const float*)d_in[15];

    float* ws    = (float*)d_ws;
    u16*   xwu   = (u16*)(ws + OFF_XW);   // LN1 out; attn_out overlay after QKV
    u16*   qbu   = (u16*)(ws + OFF_Q);
    u16*   kbu   = (u16*)(ws + OFF_K);
    u16*   vbu   = (u16*)(ws + OFF_V);
    u16*   hbu   = (u16*)(ws + OFF_Q);    // fc1 out overlays q..v (dead after attn)
    u16*   ybu   = (u16*)(ws + OFF_V);    // LN2 out overlays vT (dead after attn)
    u16*   biasw = (u16*)(ws + OFF_BF);
    u16*   wb    = (u16*)(ws + OFF_WB);
    float* xres  = (float*)d_out;

    const u16* wqkv_b  = wb;
    const u16* wproj_b = wb + 110592;
    const u16* wfc1_b  = wb + 147456;
    const u16* wfc2_b  = wb + 221184;

    k_prep<<<1536, 256, 0, stream>>>(w_qkv, w_proj, w_fc1, w_fc2, wb, rpb, rpi, biasw);
    k_ln<true><<<16384, 256, 0, stream>>>(x, gamma1, beta1, xwu);
    k_mgemm<0, 192><<<4608, 256, 0, stream>>>(xwu, wqkv_b, b_qkv, nullptr, nullptr,
                                              qbu, kbu, vbu);
    k_attn<<<3072, 256, 0, stream>>>(qbu, kbu, vbu, biasw, xwu);
    k_mgemm<1, 192><<<1536, 256, 0, stream>>>(xwu, wproj_b, b_proj, xres, x,
                                              nullptr, nullptr, nullptr);
    k_ln<false><<<16384, 256, 0, stream>>>(xres, gamma2, beta2, ybu);
    k_mgemm<2, 192><<<3072, 256, 0, stream>>>(ybu, wfc1_b, b_fc1, hbu, nullptr,
                                              nullptr, nullptr, nullptr);
    k_mgemm<3, 384><<<1536, 256, 0, stream>>>(hbu, wfc2_b, b_fc2, xres, xres,
                                              nullptr, nullptr, nullptr);
}